// Round 4
// baseline (2191.473 us; speedup 1.0000x reference)
//
#include <hip/hip_runtime.h>
#include <stdint.h>
#include <math.h>

#define NTOK 2048
#define HDIM 2048
#define FDIM 1024
#define NEXP 32
#define TOPK 4
#define NGRP 4
#define CAP  512

typedef _Float16 f16;
typedef _Float16 half8 __attribute__((ext_vector_type(8)));
typedef _Float16 half2v __attribute__((ext_vector_type(2)));
typedef float f32x4 __attribute__((ext_vector_type(4)));

__device__ __forceinline__ int swz(int r) { return (r ^ (r >> 3)) & 7; }

__device__ __forceinline__ void gll16(const void* g, void* l) {
  __builtin_amdgcn_global_load_lds((const __attribute__((address_space(1))) void*)g,
                                   (__attribute__((address_space(3))) void*)l, 16, 0, 0);
}

// ---------------- convert x (fp32) -> xb (fp16) ----------------
__global__ __launch_bounds__(256) void convert_kernel(const float* __restrict__ x,
                                                      f16* __restrict__ xb, int n8) {
  int i = blockIdx.x * 256 + threadIdx.x;
  if (i >= n8) return;
  const f32x4* p = (const f32x4*)(x + (size_t)i * 8);
  f32x4 a = p[0], b = p[1];
  half8 v;
  v[0] = (f16)a[0]; v[1] = (f16)a[1]; v[2] = (f16)a[2]; v[3] = (f16)a[3];
  v[4] = (f16)b[0]; v[5] = (f16)b[1]; v[6] = (f16)b[2]; v[7] = (f16)b[3];
  *(half8*)(xb + (size_t)i * 8) = v;
}

// ---------------- gate ----------------
__global__ __launch_bounds__(256) void gate_kernel(const float* __restrict__ x,
                                                   const float* __restrict__ gw,
                                                   const float* __restrict__ gb,
                                                   int* __restrict__ tidx,
                                                   float* __restrict__ tw) {
  int t = blockIdx.x;
  int tid = threadIdx.x;
  int e = tid >> 3, p = tid & 7;
  const float* xr = x + (size_t)t * HDIM;
  const float* wr = gw + (size_t)e * HDIM;
  float s = 0.f;
  for (int i = p; i < HDIM; i += 8) s += xr[i] * wr[i];
  s += __shfl_down(s, 4, 8);
  s += __shfl_down(s, 2, 8);
  s += __shfl_down(s, 1, 8);
  __shared__ float lg[NEXP];
  if (p == 0) lg[e] = s;
  __syncthreads();
  if (tid == 0) {
    float sc[NEXP], scb[NEXP];
    for (int i = 0; i < NEXP; i++) {
      sc[i] = 1.f / (1.f + expf(-lg[i]));
      scb[i] = sc[i] + gb[i];
    }
    float gs[NGRP];
    for (int g = 0; g < NGRP; g++) {
      float m1 = -1e30f, m2 = -1e30f;
      for (int j = 0; j < 8; j++) {
        float v = scb[g * 8 + j];
        if (v > m1) { m2 = m1; m1 = v; }
        else if (v > m2) m2 = v;
      }
      gs[g] = m1 + m2;
    }
    int g1 = 0; float bv = gs[0];
    for (int g = 1; g < NGRP; g++) if (gs[g] > bv) { bv = gs[g]; g1 = g; }
    int g2 = -1; bv = -1e30f;
    for (int g = 0; g < NGRP; g++) if (g != g1 && gs[g] > bv) { bv = gs[g]; g2 = g; }
    float cand[NEXP];
    for (int i = 0; i < NEXP; i++) {
      int g = i >> 3;
      cand[i] = (g == g1 || g == g2) ? scb[i] : 0.0f;
    }
    int isel[TOPK]; float wsel[TOPK]; float wsum = 0.f;
    bool used[NEXP] = {};
    for (int k = 0; k < TOPK; k++) {
      int best = 0; float bw = -1e30f;
      for (int i = 0; i < NEXP; i++)
        if (!used[i] && cand[i] > bw) { bw = cand[i]; best = i; }
      used[best] = true;
      isel[k] = best;
      wsel[k] = sc[best];
      wsum += wsel[k];
    }
    float inv = 2.0f / (wsum + 1e-20f);
    for (int k = 0; k < TOPK; k++) {
      tidx[t * TOPK + k] = isel[k];
      tw[t * TOPK + k] = wsel[k] * inv;
    }
  }
}

// ---------------- dispatch ----------------
__global__ __launch_bounds__(256) void dispatch_kernel(const int* __restrict__ tidx,
                                                       const float* __restrict__ tw,
                                                       int* __restrict__ tok,
                                                       float* __restrict__ wt,
                                                       int* __restrict__ cnt) {
  int e = blockIdx.x, tid = threadIdx.x, wv = tid >> 6, lane = tid & 63;
  __shared__ int wsum[4];
  __shared__ int sbase;
  if (tid == 0) sbase = 0;
  __syncthreads();
  for (int c = 0; c < (NTOK * TOPK) / 256; c++) {
    int i = c * 256 + tid;
    int fe = tidx[i];
    bool flag = (fe == e);
    unsigned long long b = __ballot(flag ? 1 : 0);
    int lr = __popcll(b & ((1ull << lane) - 1ull));
    if (lane == 0) wsum[wv] = __popcll(b);
    __syncthreads();
    int off = 0;
    for (int w2 = 0; w2 < wv; w2++) off += wsum[w2];
    int tot = wsum[0] + wsum[1] + wsum[2] + wsum[3];
    int base = sbase;
    if (flag) {
      int pos = base + off + lr;
      if (pos < CAP) {
        tok[e * CAP + pos] = i >> 2;
        wt[e * CAP + pos] = tw[i];
      }
    }
    __syncthreads();
    if (tid == 0) sbase = base + tot;
  }
  __syncthreads();
  if (tid == 0) cnt[e] = min(sbase, CAP);
}

// ---------------- BM=64 pipelined MFMA GEMM, 2-deep B prefetch ----------------
// MODE 0: routed up (dual w1/w3, gathered A, silu-mul -> h fp16)
// MODE 1: shared up (dual sg/su, linear A, -> hs fp16)
// MODE 2: routed down (w2, A=h[e], atomicAdd out)
// MODE 3: shared down (sd, A=hs, plain store out)
template<int MODE, int BN>
__global__ __launch_bounds__(256, 3) void gemm_kernel(
    const f16* __restrict__ Abase, const float* __restrict__ B0g, const float* __restrict__ B1g,
    void* __restrict__ OutP, const int* __restrict__ tokL, const float* __restrict__ wtL,
    const int* __restrict__ cntP, int MX, int NY, int K, int N, int ldA) {
  constexpr int BM = 64, BK = 64;
  constexpr bool DUAL = (MODE == 0 || MODE == 1);
  constexpr bool ROUTED = (MODE == 0 || MODE == 2);
  constexpr int NF = BN / 32;
  constexpr int WN = BN / 2;
  constexpr int TPR = BN / 4;      // threads per k-row (float4)
  constexpr int RPI = 512 / TPR;   // k-rows per iter (2 per thread)
  constexpr int ITER = BK / RPI;
  constexpr int BSZ = BN * 128 * (DUAL ? 2 : 1);

  // XCD-chunked decode: consecutive tiles (sharing B slices) on same XCD
  int G = gridDim.x;
  int id = blockIdx.x;
  int tile = (id & 7) * (G >> 3) + (id >> 3);
  int xm = tile % MX;
  int t2 = tile / MX;
  int yn = t2 % NY;
  int e = t2 / NY;

  int m0 = xm * BM, n0 = yn * BN;
  int Mcur = 1 << 30;
  const f16* A = Abase;
  const float* B0 = B0g;
  const float* B1 = B1g;
  const int* tok = tokL;
  const float* wtl = wtL;
  if (ROUTED) {
    Mcur = cntP[e];
    if (m0 >= Mcur) return;
    B0 += (size_t)e * K * N;
    if (DUAL) B1 += (size_t)e * K * N;
    tok += e * CAP;
    wtl += e * CAP;
    if (MODE == 2) A += (size_t)e * CAP * (size_t)ldA;
  }

  __shared__ __align__(16) char smem[16384 + 2 * BSZ];

  int tid = threadIdx.x, lane = tid & 63, wv = tid >> 6;
  int wm = (wv >> 1) * 32, wn = (wv & 1) * WN;

  // A gll sources: linear LDS dest, pre-swizzled global src
  const f16* asrc[2];
#pragma unroll
  for (int j = 0; j < 2; j++) {
    int r = j * 32 + wv * 8 + (lane >> 3);
    int c = (lane & 7) ^ swz(r);
    int gr = m0 + r;
    const f16* base;
    if (MODE == 0) {
      int rr = gr < Mcur ? gr : (Mcur - 1);
      base = A + (size_t)tok[rr] * ldA;
    } else {
      base = A + (size_t)gr * ldA;
    }
    asrc[j] = base + c * 8;
  }

  // 2-deep B register staging, compile-time slots (no runtime reg indexing)
  f32x4 brA0[2 * ITER], brA1[DUAL ? 2 * ITER : 1];   // slot 0
  f32x4 brB0[2 * ITER], brB1[DUAL ? 2 * ITER : 1];   // slot 1

  f32x4 acc0[2][NF];
  f32x4 acc1[2][NF];
#pragma unroll
  for (int mf = 0; mf < 2; mf++)
#pragma unroll
    for (int nf = 0; nf < NF; nf++) {
      acc0[mf][nf] = (f32x4){0.f, 0.f, 0.f, 0.f};
      acc1[mf][nf] = (f32x4){0.f, 0.f, 0.f, 0.f};
    }

  int kp0 = 2 * (tid / TPR);
  int nn0 = 4 * (tid % TPR);

  auto loadA = [&](int t) {   // 2 VMEM -> LDS_A[t&1]
#pragma unroll
    for (int j = 0; j < 2; j++)
      gll16(asrc[j] + (size_t)t * BK, smem + (t & 1) * 8192 + j * 4096 + wv * 1024 + lane * 16);
  };

#define LOADB(S) { \
    int k0 = (tG) * BK; \
    _Pragma("unroll") \
    for (int i = 0; i < ITER; i++) { \
      int kp = kp0 + i * RPI; \
      const float* s0 = B0 + (size_t)(k0 + kp) * N + n0 + nn0; \
      br##S##0[2 * i] = *(const f32x4*)s0; \
      br##S##0[2 * i + 1] = *(const f32x4*)(s0 + N); \
      if constexpr (DUAL) { \
        const float* s1 = B1 + (size_t)(k0 + kp) * N + n0 + nn0; \
        br##S##1[2 * i] = *(const f32x4*)s1; \
        br##S##1[2 * i + 1] = *(const f32x4*)(s1 + N); \
      } \
    } }

#define WRITEB(S, P) { \
    char* Bs0 = smem + 16384 + (P) * BSZ; \
    char* Bs1 = Bs0 + BN * 128; \
    _Pragma("unroll") \
    for (int i = 0; i < ITER; i++) { \
      int kp = kp0 + i * RPI; \
      _Pragma("unroll") \
      for (int q = 0; q < 4; q++) { \
        int n = nn0 + q; \
        int off = n * 128 + (((kp >> 3) ^ swz(n)) << 4) + (kp & 7) * 2; \
        half2v h0; \
        h0[0] = (f16)br##S##0[2 * i][q]; \
        h0[1] = (f16)br##S##0[2 * i + 1][q]; \
        *(half2v*)(Bs0 + off) = h0; \
        if constexpr (DUAL) { \
          half2v h1; \
          h1[0] = (f16)br##S##1[2 * i][q]; \
          h1[1] = (f16)br##S##1[2 * i + 1][q]; \
          *(half2v*)(Bs1 + off) = h1; \
        } \
      } \
    } }

  auto compute = [&](int ap, int bp) {   // A-buf parity, B-slot parity (compile-time at callsites)
    char* Ab = smem + ap * 8192;
    char* Bs0 = smem + 16384 + bp * BSZ;
    char* Bs1 = Bs0 + BN * 128;
#pragma unroll
    for (int kk = 0; kk < 2; kk++) {
      half8 af[2];
#pragma unroll
      for (int mf = 0; mf < 2; mf++) {
        int r = wm + mf * 16 + (lane & 15);
        af[mf] = *(const half8*)(Ab + r * 128 + ((((kk << 2) + (lane >> 4)) ^ swz(r)) << 4));
      }
      half8 bf0[NF], bf1[NF];
#pragma unroll
      for (int nf = 0; nf < NF; nf++) {
        int n = wn + nf * 16 + (lane & 15);
        int off = n * 128 + ((((kk << 2) + (lane >> 4)) ^ swz(n)) << 4);
        bf0[nf] = *(const half8*)(Bs0 + off);
        if constexpr (DUAL) bf1[nf] = *(const half8*)(Bs1 + off);
      }
#pragma unroll
      for (int mf = 0; mf < 2; mf++)
#pragma unroll
        for (int nf = 0; nf < NF; nf++) {
          acc0[mf][nf] = __builtin_amdgcn_mfma_f32_16x16x32_f16(af[mf], bf0[nf], acc0[mf][nf], 0, 0, 0);
          if constexpr (DUAL)
            acc1[mf][nf] = __builtin_amdgcn_mfma_f32_16x16x32_f16(af[mf], bf1[nf], acc1[mf][nf], 0, 0, 0);
        }
    }
  };

  int nk = K / BK;   // 32 or 16, always even
  // Prologue
  { int tG = 0; LOADB(A) }
  { int tG = 1; LOADB(B) }
  loadA(0);
  WRITEB(A, 0)                         // auto-waits B(0) regs only
  { int tG = 2; LOADB(A) }
  asm volatile("s_waitcnt vmcnt(8) lgkmcnt(0)" ::: "memory");  // A(0)+writes done; B(2) flying
  __builtin_amdgcn_s_barrier();

  for (int t = 0; t < nk; t += 2) {
    // ---- tile t (A-buf t&1=0-parity ap=t&1? use compile-time parity per sub-iter) ----
    {
      loadA(t + 1);
      WRITEB(B, 1)                     // publish B(t+1) into slot-LDS 1
      bool more = (t + 3 < nk);
      if (more) { int tG = t + 3; LOADB(B) }
      compute((t & 1), 0);             // t even -> A-buf 0, B-LDS 0
      if (more) asm volatile("s_waitcnt vmcnt(8) lgkmcnt(0)" ::: "memory");
      else      asm volatile("s_waitcnt vmcnt(0) lgkmcnt(0)" ::: "memory");
      __builtin_amdgcn_s_barrier();
    }
    // ---- tile t+1 ----
    {
      bool last = (t + 2 >= nk);
      if (!last) {
        loadA(t + 2);
        WRITEB(A, 0)
        bool more = (t + 4 < nk);
        if (more) { int tG = t + 4; LOADB(A) }
        compute(1, 1);
        if (more) asm volatile("s_waitcnt vmcnt(8) lgkmcnt(0)" ::: "memory");
        else      asm volatile("s_waitcnt vmcnt(0) lgkmcnt(0)" ::: "memory");
        __builtin_amdgcn_s_barrier();
      } else {
        compute(1, 1);
      }
    }
  }

#undef LOADB
#undef WRITEB

  // epilogue
  if (MODE == 0 || MODE == 1) {
    f16* Hout = (f16*)OutP;
    if (MODE == 0) Hout += (size_t)e * CAP * FDIM;
#pragma unroll
    for (int mf = 0; mf < 2; mf++) {
      int rb = wm + mf * 16 + ((lane >> 4) << 2);
#pragma unroll
      for (int j = 0; j < 4; j++) {
        int slot = m0 + rb + j;
        if (MODE == 0 && slot >= Mcur) continue;
#pragma unroll
        for (int nf = 0; nf < NF; nf++) {
          int col = n0 + wn + nf * 16 + (lane & 15);
          float g = acc0[mf][nf][j], u = acc1[mf][nf][j];
          float val = g / (1.f + expf(-g)) * u;
          Hout[(size_t)slot * N + col] = (f16)val;
        }
      }
    }
  } else {
    float* Of = (float*)OutP;
#pragma unroll
    for (int mf = 0; mf < 2; mf++) {
      int rb = wm + mf * 16 + ((lane >> 4) << 2);
#pragma unroll
      for (int j = 0; j < 4; j++) {
        int slot = m0 + rb + j;
        if (MODE == 2) {
          if (slot >= Mcur) continue;
          int tk = tok[slot];
          float w = wtl[slot];
#pragma unroll
          for (int nf = 0; nf < NF; nf++) {
            int col = n0 + wn + nf * 16 + (lane & 15);
            atomicAdd(&Of[(size_t)tk * HDIM + col], acc0[mf][nf][j] * w);
          }
        } else {
#pragma unroll
          for (int nf = 0; nf < NF; nf++) {
            int col = n0 + wn + nf * 16 + (lane & 15);
            Of[(size_t)slot * N + col] = acc0[mf][nf][j];
          }
        }
      }
    }
  }
}

// ---------------- launch ----------------
extern "C" void kernel_launch(void* const* d_in, const int* in_sizes, int n_in,
                              void* d_out, int out_size, void* d_ws, size_t ws_size,
                              hipStream_t stream) {
  const float* x  = (const float*)d_in[0];
  const float* gw = (const float*)d_in[1];
  const float* gb = (const float*)d_in[2];
  const float* w1 = (const float*)d_in[3];
  const float* w2 = (const float*)d_in[4];
  const float* w3 = (const float*)d_in[5];
  const float* sg = (const float*)d_in[6];
  const float* su = (const float*)d_in[7];
  const float* sd = (const float*)d_in[8];
  float* out = (float*)d_out;
  char* ws = (char*)d_ws;

  f16*   xb   = (f16*)(ws);                      // 8,388,608 B
  f16*   hs   = (f16*)(ws + 8388608);            // 8,388,608 B
  f16*   hbuf = (f16*)(ws + 16777216);           // 33,554,432 B
  int*   tok  = (int*)(ws + 50331648);
  float* wt   = (float*)(ws + 50397184);
  int*   tidx = (int*)(ws + 50462720);
  float* tw   = (float*)(ws + 50495488);
  int*   cnt  = (int*)(ws + 50528256);

  convert_kernel<<<2048, 256, 0, stream>>>(x, xb, 524288);
  gate_kernel<<<2048, 256, 0, stream>>>(x, gw, gb, tidx, tw);
  dispatch_kernel<<<32, 256, 0, stream>>>(tidx, tw, tok, wt, cnt);

  // routed up: h = silu(Xe@w1)*(Xe@w3)   [K=2048, N=1024]  grid 8x16x32
  gemm_kernel<0, 64><<<4096, 256, 0, stream>>>(
      xb, w1, w3, hbuf, tok, wt, cnt, 8, 16, 2048, 1024, 2048);
  // shared up: hs = silu(x@sg)*(x@su)    [K=2048, N=2048]  grid 32x32
  gemm_kernel<1, 64><<<1024, 256, 0, stream>>>(
      xb, sg, su, hs, nullptr, nullptr, nullptr, 32, 32, 2048, 2048, 2048);
  // shared down: out = hs @ sd           [K=2048, N=2048]  grid 32x32
  gemm_kernel<3, 64><<<1024, 256, 0, stream>>>(
      hs, sd, nullptr, out, nullptr, nullptr, nullptr, 32, 32, 2048, 2048, 2048);
  // routed down: out += w * (h @ w2)     [K=1024, N=2048]  grid 8x16x32
  gemm_kernel<2, 128><<<4096, 256, 0, stream>>>(
      hbuf, w2, nullptr, out, tok, wt, cnt, 8, 16, 1024, 2048, 1024);
}

// Round 5
// 758.346 us; speedup vs baseline: 2.8898x; 2.8898x over previous
//
#include <hip/hip_runtime.h>
#include <stdint.h>
#include <math.h>

#define NTOK 2048
#define HDIM 2048
#define FDIM 1024
#define FSD  2048
#define NEXP 32
#define TOPK 4
#define NGRP 4
#define CAP  512

typedef _Float16 f16;
typedef _Float16 half8 __attribute__((ext_vector_type(8)));
typedef float f32x4 __attribute__((ext_vector_type(4)));

__device__ __forceinline__ int swz3(int r) { return (r ^ (r >> 2)) & 3; }

__device__ __forceinline__ void gll16(const void* g, void* l) {
  __builtin_amdgcn_global_load_lds((const __attribute__((address_space(1))) void*)g,
                                   (__attribute__((address_space(3))) void*)l, 16, 0, 0);
}

// ---------------- convert x (fp32) -> xb (fp16) ----------------
__global__ __launch_bounds__(256) void convert_kernel(const float* __restrict__ x,
                                                      f16* __restrict__ xb, int n8) {
  int i = blockIdx.x * 256 + threadIdx.x;
  if (i >= n8) return;
  const f32x4* p = (const f32x4*)(x + (size_t)i * 8);
  f32x4 a = p[0], b = p[1];
  half8 v;
  v[0] = (f16)a[0]; v[1] = (f16)a[1]; v[2] = (f16)a[2]; v[3] = (f16)a[3];
  v[4] = (f16)b[0]; v[5] = (f16)b[1]; v[6] = (f16)b[2]; v[7] = (f16)b[3];
  *(half8*)(xb + (size_t)i * 8) = v;
}

// ---------------- gate ----------------
__global__ __launch_bounds__(256) void gate_kernel(const float* __restrict__ x,
                                                   const float* __restrict__ gw,
                                                   const float* __restrict__ gb,
                                                   int* __restrict__ tidx,
                                                   float* __restrict__ tw) {
  int t = blockIdx.x;
  int tid = threadIdx.x;
  int e = tid >> 3, p = tid & 7;
  const float* xr = x + (size_t)t * HDIM;
  const float* wr = gw + (size_t)e * HDIM;
  float s = 0.f;
  for (int i = p; i < HDIM; i += 8) s += xr[i] * wr[i];
  s += __shfl_down(s, 4, 8);
  s += __shfl_down(s, 2, 8);
  s += __shfl_down(s, 1, 8);
  __shared__ float lg[NEXP];
  if (p == 0) lg[e] = s;
  __syncthreads();
  if (tid == 0) {
    float sc[NEXP], scb[NEXP];
    for (int i = 0; i < NEXP; i++) {
      sc[i] = 1.f / (1.f + expf(-lg[i]));
      scb[i] = sc[i] + gb[i];
    }
    float gs[NGRP];
    for (int g = 0; g < NGRP; g++) {
      float m1 = -1e30f, m2 = -1e30f;
      for (int j = 0; j < 8; j++) {
        float v = scb[g * 8 + j];
        if (v > m1) { m2 = m1; m1 = v; }
        else if (v > m2) m2 = v;
      }
      gs[g] = m1 + m2;
    }
    int g1 = 0; float bv = gs[0];
    for (int g = 1; g < NGRP; g++) if (gs[g] > bv) { bv = gs[g]; g1 = g; }
    int g2 = -1; bv = -1e30f;
    for (int g = 0; g < NGRP; g++) if (g != g1 && gs[g] > bv) { bv = gs[g]; g2 = g; }
    float cand[NEXP];
    for (int i = 0; i < NEXP; i++) {
      int g = i >> 3;
      cand[i] = (g == g1 || g == g2) ? scb[i] : 0.0f;
    }
    int isel[TOPK]; float wsel[TOPK]; float wsum = 0.f;
    bool used[NEXP] = {};
    for (int k = 0; k < TOPK; k++) {
      int best = 0; float bw = -1e30f;
      for (int i = 0; i < NEXP; i++)
        if (!used[i] && cand[i] > bw) { bw = cand[i]; best = i; }
      used[best] = true;
      isel[k] = best;
      wsel[k] = sc[best];
      wsum += wsel[k];
    }
    float inv = 2.0f / (wsum + 1e-20f);
    for (int k = 0; k < TOPK; k++) {
      tidx[t * TOPK + k] = isel[k];
      tw[t * TOPK + k] = wsel[k] * inv;
    }
  }
}

// ---------------- dispatch ----------------
__global__ __launch_bounds__(256) void dispatch_kernel(const int* __restrict__ tidx,
                                                       const float* __restrict__ tw,
                                                       int* __restrict__ tok,
                                                       float* __restrict__ wt,
                                                       int* __restrict__ cnt) {
  int e = blockIdx.x, tid = threadIdx.x, wv = tid >> 6, lane = tid & 63;
  __shared__ int wsum[4];
  __shared__ int sbase;
  if (tid == 0) sbase = 0;
  __syncthreads();
  for (int c = 0; c < (NTOK * TOPK) / 256; c++) {
    int i = c * 256 + tid;
    int fe = tidx[i];
    bool flag = (fe == e);
    unsigned long long b = __ballot(flag ? 1 : 0);
    int lr = __popcll(b & ((1ull << lane) - 1ull));
    if (lane == 0) wsum[wv] = __popcll(b);
    __syncthreads();
    int off = 0;
    for (int w2 = 0; w2 < wv; w2++) off += wsum[w2];
    int tot = wsum[0] + wsum[1] + wsum[2] + wsum[3];
    int base = sbase;
    if (flag) {
      int pos = base + off + lr;
      if (pos < CAP) {
        tok[e * CAP + pos] = i >> 2;
        wt[e * CAP + pos] = tw[i];
      }
    }
    __syncthreads();
    if (tid == 0) sbase = base + tot;
  }
  __syncthreads();
  if (tid == 0) cnt[e] = min(sbase, CAP);
}

// ---------------- BM=256/BN=32/BK=32 counted-vmcnt GEMM ----------------
// One block per (expert|m-chunk, n-slice); all blocks alive.
// MODE 0: routed up (dual w1/w3, gathered A, silu-mul -> hbuf fp16)
// MODE 1: shared up (dual sg/su, linear A, -> hs fp16)
// MODE 2: routed down (w2, A=hbuf[e], atomicAdd out)
// MODE 3: shared down (sd, A=hs, plain store out)
template<int MODE>
__global__ __launch_bounds__(256, 3) void gemm_kernel(
    const f16* __restrict__ Abase, const float* __restrict__ B0g, const float* __restrict__ B1g,
    void* __restrict__ OutP, const int* __restrict__ tokL, const float* __restrict__ wtL,
    const int* __restrict__ cntP, int K, int N, int ldA, int ntb) {
  constexpr int BM = 256, BN = 32, BK = 32;
  constexpr bool DUAL = (MODE == 0 || MODE == 1);
  constexpr bool ROUTED = (MODE == 0 || MODE == 2);
  constexpr int NB = DUAL ? 2 : 1;   // B VMEM ops per thread per tile

  int bid = blockIdx.x;
  int yn = bid & ((1 << ntb) - 1);
  int rest = bid >> ntb;
  int n0 = yn * BN;

  int Mcur = 1 << 30, mstart, mend;
  const f16* A = Abase;
  const float* B0 = B0g;
  const float* B1 = B1g;
  const int* tok = tokL;
  const float* wtl = wtL;
  if (ROUTED) {
    int e = rest;
    Mcur = cntP[e];
    B0 += (size_t)e * K * N;
    if (DUAL) B1 += (size_t)e * K * N;
    tok += e * CAP;
    wtl += e * CAP;
    if (MODE == 2) A += (size_t)e * CAP * (size_t)ldA;
    mstart = 0; mend = Mcur;
  } else {
    mstart = rest * BM; mend = mstart + BM;
  }

  // LDS: A dbuf 2x16KB | B dbuf 2x(NB*2KB)
  __shared__ __align__(16) char smem[32768 + 2 * NB * 2048];
  char* Bbase = smem + 32768;

  int tid = threadIdx.x, lane = tid & 63, wv = tid >> 6;
  int wm = wv * 64;

  int kb = tid >> 3;          // B k-row 0..31
  int nb4 = (tid & 7) * 4;    // B n offset

  int nk = K / BK;

  for (int m0 = mstart; m0 < mend; m0 += BM) {
    // A gll sources: linear LDS dest, pre-swizzled global src
    const f16* asrc[4];
#pragma unroll
    for (int j = 0; j < 4; j++) {
      int r = j * 64 + (tid >> 2);
      int c = (tid & 3) ^ swz3(r);
      int gr = m0 + r;
      const f16* base;
      if (MODE == 0) {
        int rr = gr < Mcur ? gr : (Mcur - 1);
        base = A + (size_t)tok[rr] * ldA;
      } else {
        base = A + (size_t)gr * ldA;
      }
      asrc[j] = base + c * 8;
    }

    f32x4 br0, br1;
    f32x4 acc0[4][2], acc1[4][2];
#pragma unroll
    for (int mf = 0; mf < 4; mf++)
#pragma unroll
      for (int nf = 0; nf < 2; nf++) {
        acc0[mf][nf] = (f32x4){0.f, 0.f, 0.f, 0.f};
        acc1[mf][nf] = (f32x4){0.f, 0.f, 0.f, 0.f};
      }

    auto loadA = [&](int t) {   // 4 gll per thread -> LDS_A[t&1]
#pragma unroll
      for (int j = 0; j < 4; j++)
        gll16(asrc[j] + (size_t)t * BK, smem + (t & 1) * 16384 + j * 4096 + tid * 16);
    };
    auto loadB = [&](int t) {   // NB f32x4 per thread
      const float* s0 = B0 + (size_t)(t * BK + kb) * N + n0 + nb4;
      br0 = *(const f32x4*)s0;
      if constexpr (DUAL) {
        const float* s1 = B1 + (size_t)(t * BK + kb) * N + n0 + nb4;
        br1 = *(const f32x4*)s1;
      }
    };
    auto writeB = [&](int t) {  // regs -> LDS_B[t&1], fp16 transpose scatter
      char* Bs0 = Bbase + (t & 1) * (NB * 2048);
#pragma unroll
      for (int q = 0; q < 4; q++) {
        int n = nb4 + q;
        int off = n * 64 + (((kb >> 3) ^ swz3(n)) << 4) + (kb & 7) * 2;
        *(f16*)(Bs0 + off) = (f16)br0[q];
        if constexpr (DUAL) *(f16*)(Bs0 + 2048 + off) = (f16)br1[q];
      }
    };
    auto compute = [&](int t) {
      char* Ab = smem + (t & 1) * 16384;
      char* Bs0 = Bbase + (t & 1) * (NB * 2048);
      half8 af[4];
#pragma unroll
      for (int mf = 0; mf < 4; mf++) {
        int r = wm + mf * 16 + (lane & 15);
        af[mf] = *(const half8*)(Ab + r * 64 + (((lane >> 4) ^ swz3(r)) << 4));
      }
      half8 bf0[2], bf1[2];
#pragma unroll
      for (int nf = 0; nf < 2; nf++) {
        int n = nf * 16 + (lane & 15);
        int off = n * 64 + (((lane >> 4) ^ swz3(n)) << 4);
        bf0[nf] = *(const half8*)(Bs0 + off);
        if constexpr (DUAL) bf1[nf] = *(const half8*)(Bs0 + 2048 + off);
      }
#pragma unroll
      for (int mf = 0; mf < 4; mf++)
#pragma unroll
        for (int nf = 0; nf < 2; nf++) {
          acc0[mf][nf] = __builtin_amdgcn_mfma_f32_16x16x32_f16(af[mf], bf0[nf], acc0[mf][nf], 0, 0, 0);
          if constexpr (DUAL)
            acc1[mf][nf] = __builtin_amdgcn_mfma_f32_16x16x32_f16(af[mf], bf1[nf], acc1[mf][nf], 0, 0, 0);
        }
    };

    // Prologue: queue order matters for the counted waits.
    loadB(0);
    asm volatile("" ::: "memory");
    writeB(0);                    // compiler auto-waits B(0) regs
    asm volatile("" ::: "memory");
    loadA(0);
    asm volatile("" ::: "memory");
    if (nk > 1) loadB(1);
    if constexpr (NB == 2) asm volatile("s_waitcnt vmcnt(2) lgkmcnt(0)" ::: "memory");
    else                   asm volatile("s_waitcnt vmcnt(1) lgkmcnt(0)" ::: "memory");
    __builtin_amdgcn_s_barrier();

    for (int t = 0; t < nk; t++) {
      // entry: LDS[t&1] = tile t; outstanding VMEM = B(t+1) regs (NB) if present
      if (t + 1 < nk) {
        loadA(t + 1);             // 4 gll -> LDS_A[(t+1)&1]
        asm volatile("" ::: "memory");
        writeB(t + 1);            // auto vmcnt(4): drains B(t+1), A still flying
        asm volatile("" ::: "memory");
        if (t + 2 < nk) loadB(t + 2);
        asm volatile("" ::: "memory");
      }
      compute(t);
      if (t + 1 < nk) {
        if (t + 2 < nk) {
          if constexpr (NB == 2) asm volatile("s_waitcnt vmcnt(2) lgkmcnt(0)" ::: "memory");
          else                   asm volatile("s_waitcnt vmcnt(1) lgkmcnt(0)" ::: "memory");
        } else {
          asm volatile("s_waitcnt vmcnt(0) lgkmcnt(0)" ::: "memory");
        }
        __builtin_amdgcn_s_barrier();
      }
    }

    // epilogue for this m-pass
    if (MODE == 0 || MODE == 1) {
      f16* Hout = (f16*)OutP;
      if (MODE == 0) Hout += (size_t)(tok - tokL) / CAP * 0;  // (base offset applied below)
      if (MODE == 0) Hout = (f16*)OutP + (size_t)rest * CAP * FDIM;
#pragma unroll
      for (int mf = 0; mf < 4; mf++) {
        int rb = wm + mf * 16 + ((lane >> 4) << 2);
#pragma unroll
        for (int j = 0; j < 4; j++) {
          int grow = m0 + rb + j;
          if (MODE == 0 && grow >= Mcur) continue;
#pragma unroll
          for (int nf = 0; nf < 2; nf++) {
            int col = n0 + nf * 16 + (lane & 15);
            float g = acc0[mf][nf][j], u = acc1[mf][nf][j];
            float val = g / (1.f + expf(-g)) * u;
            Hout[(size_t)grow * N + col] = (f16)val;
          }
        }
      }
    } else {
      float* Of = (float*)OutP;
#pragma unroll
      for (int mf = 0; mf < 4; mf++) {
        int rb = wm + mf * 16 + ((lane >> 4) << 2);
#pragma unroll
        for (int j = 0; j < 4; j++) {
          int grow = m0 + rb + j;
          if (MODE == 2) {
            if (grow >= Mcur) continue;
            int tk = tok[grow];
            float w = wtl[grow];
#pragma unroll
            for (int nf = 0; nf < 2; nf++) {
              int col = n0 + nf * 16 + (lane & 15);
              atomicAdd(&Of[(size_t)tk * HDIM + col], acc0[mf][nf][j] * w);
            }
          } else {
#pragma unroll
            for (int nf = 0; nf < 2; nf++) {
              int col = n0 + nf * 16 + (lane & 15);
              Of[(size_t)grow * N + col] = acc0[mf][nf][j];
            }
          }
        }
      }
    }
  }
}

// ---------------- launch ----------------
extern "C" void kernel_launch(void* const* d_in, const int* in_sizes, int n_in,
                              void* d_out, int out_size, void* d_ws, size_t ws_size,
                              hipStream_t stream) {
  const float* x  = (const float*)d_in[0];
  const float* gw = (const float*)d_in[1];
  const float* gb = (const float*)d_in[2];
  const float* w1 = (const float*)d_in[3];
  const float* w2 = (const float*)d_in[4];
  const float* w3 = (const float*)d_in[5];
  const float* sg = (const float*)d_in[6];
  const float* su = (const float*)d_in[7];
  const float* sd = (const float*)d_in[8];
  float* out = (float*)d_out;
  char* ws = (char*)d_ws;

  f16*   xb   = (f16*)(ws);                      // 8,388,608 B
  f16*   hs   = (f16*)(ws + 8388608);            // 8,388,608 B
  f16*   hbuf = (f16*)(ws + 16777216);           // 33,554,432 B
  int*   tok  = (int*)(ws + 50331648);
  float* wt   = (float*)(ws + 50397184);
  int*   tidx = (int*)(ws + 50462720);
  float* tw   = (float*)(ws + 50495488);
  int*   cnt  = (int*)(ws + 50528256);

  convert_kernel<<<2048, 256, 0, stream>>>(x, xb, 524288);
  gate_kernel<<<2048, 256, 0, stream>>>(x, gw, gb, tidx, tw);
  dispatch_kernel<<<32, 256, 0, stream>>>(tidx, tw, tok, wt, cnt);

  // routed up: hbuf = silu(Xe@w1)*(Xe@w3)  [K=2048,N=1024]; grid = 32 n-tiles x 32 experts
  gemm_kernel<0><<<1024, 256, 0, stream>>>(
      xb, w1, w3, hbuf, tok, wt, cnt, 2048, 1024, 2048, 5);
  // shared up: hs = silu(x@sg)*(x@su)      [K=2048,N=2048]; grid = 64 n x 8 m-chunks
  gemm_kernel<1><<<512, 256, 0, stream>>>(
      xb, sg, su, hs, nullptr, nullptr, nullptr, 2048, 2048, 2048, 6);
  // shared down: out = hs @ sd             [K=2048,N=2048]; grid = 64 n x 8 m-chunks
  gemm_kernel<3><<<512, 256, 0, stream>>>(
      hs, sd, nullptr, out, nullptr, nullptr, nullptr, 2048, 2048, 2048, 6);
  // routed down: out += w * (hbuf @ w2)    [K=1024,N=2048]; grid = 64 n x 32 experts
  gemm_kernel<2><<<2048, 256, 0, stream>>>(
      hbuf, w2, nullptr, out, tok, wt, cnt, 1024, 2048, 1024, 6);
}

// Round 6
// 564.620 us; speedup vs baseline: 3.8813x; 1.3431x over previous
//
#include <hip/hip_runtime.h>
#include <stdint.h>
#include <math.h>

#define NTOK 2048
#define HDIM 2048
#define FDIM 1024
#define NEXP 32
#define TOPK 4
#define NGRP 4
#define CAP  512

typedef _Float16 f16;
typedef _Float16 half8 __attribute__((ext_vector_type(8)));
typedef float f32x4 __attribute__((ext_vector_type(4)));

__device__ __forceinline__ int swz3(int r) { return (r ^ (r >> 2)) & 3; }

// ---------------- convert x fp32 [2048][2048] -> xbt fp16 k-chunked [64][2048][32] ----------------
__global__ __launch_bounds__(256) void convert_kernel(const float* __restrict__ x,
                                                      f16* __restrict__ xbt) {
  int i = blockIdx.x * 256 + threadIdx.x;
  int r = i >> 8;
  int c8 = (i & 255) << 3;
  const float* p = x + (size_t)r * HDIM + c8;
  f32x4 a = *(const f32x4*)p;
  f32x4 b = *(const f32x4*)(p + 4);
  half8 v;
  v[0] = (f16)a[0]; v[1] = (f16)a[1]; v[2] = (f16)a[2]; v[3] = (f16)a[3];
  v[4] = (f16)b[0]; v[5] = (f16)b[1]; v[6] = (f16)b[2]; v[7] = (f16)b[3];
  int t = c8 >> 5;
  *(half8*)((char*)xbt + (size_t)t * 131072 + r * 64 + (c8 & 31) * 2) = v;
}

// ---------------- gate ----------------
__global__ __launch_bounds__(256) void gate_kernel(const float* __restrict__ x,
                                                   const float* __restrict__ gw,
                                                   const float* __restrict__ gb,
                                                   int* __restrict__ tidx,
                                                   float* __restrict__ tw) {
  int t = blockIdx.x;
  int tid = threadIdx.x;
  int e = tid >> 3, p = tid & 7;
  const f32x4* xr = (const f32x4*)(x + (size_t)t * HDIM);
  const f32x4* wr = (const f32x4*)(gw + (size_t)e * HDIM);
  float s = 0.f;
  for (int c = 0; c < 64; c++) {
    f32x4 a = xr[p + c * 8], w = wr[p + c * 8];
    s += a[0] * w[0] + a[1] * w[1] + a[2] * w[2] + a[3] * w[3];
  }
  s += __shfl_down(s, 4, 8);
  s += __shfl_down(s, 2, 8);
  s += __shfl_down(s, 1, 8);
  __shared__ float lg[NEXP];
  if (p == 0) lg[e] = s;
  __syncthreads();
  if (tid == 0) {
    float sc[NEXP], scb[NEXP];
    for (int i = 0; i < NEXP; i++) {
      sc[i] = 1.f / (1.f + expf(-lg[i]));
      scb[i] = sc[i] + gb[i];
    }
    float gs[NGRP];
    for (int g = 0; g < NGRP; g++) {
      float m1 = -1e30f, m2 = -1e30f;
      for (int j = 0; j < 8; j++) {
        float v = scb[g * 8 + j];
        if (v > m1) { m2 = m1; m1 = v; }
        else if (v > m2) m2 = v;
      }
      gs[g] = m1 + m2;
    }
    int g1 = 0; float bv = gs[0];
    for (int g = 1; g < NGRP; g++) if (gs[g] > bv) { bv = gs[g]; g1 = g; }
    int g2 = -1; bv = -1e30f;
    for (int g = 0; g < NGRP; g++) if (g != g1 && gs[g] > bv) { bv = gs[g]; g2 = g; }
    float cand[NEXP];
    for (int i = 0; i < NEXP; i++) {
      int g = i >> 3;
      cand[i] = (g == g1 || g == g2) ? scb[i] : 0.0f;
    }
    int isel[TOPK]; float wsel[TOPK]; float wsum = 0.f;
    bool used[NEXP] = {};
    for (int k = 0; k < TOPK; k++) {
      int best = 0; float bw = -1e30f;
      for (int i = 0; i < NEXP; i++)
        if (!used[i] && cand[i] > bw) { bw = cand[i]; best = i; }
      used[best] = true;
      isel[k] = best;
      wsel[k] = sc[best];
      wsum += wsel[k];
    }
    float inv = 2.0f / (wsum + 1e-20f);
    for (int k = 0; k < TOPK; k++) {
      tidx[t * TOPK + k] = isel[k];
      tw[t * TOPK + k] = wsel[k] * inv;
    }
  }
}

// ---------------- dispatch ----------------
__global__ __launch_bounds__(256) void dispatch_kernel(const int* __restrict__ tidx,
                                                       const float* __restrict__ tw,
                                                       int* __restrict__ tok,
                                                       float* __restrict__ wt,
                                                       int* __restrict__ cnt) {
  int e = blockIdx.x, tid = threadIdx.x, wv = tid >> 6, lane = tid & 63;
  __shared__ int wsum[4];
  __shared__ int sbase;
  if (tid == 0) sbase = 0;
  __syncthreads();
  for (int c = 0; c < (NTOK * TOPK) / 256; c++) {
    int i = c * 256 + tid;
    int fe = tidx[i];
    bool flag = (fe == e);
    unsigned long long b = __ballot(flag ? 1 : 0);
    int lr = __popcll(b & ((1ull << lane) - 1ull));
    if (lane == 0) wsum[wv] = __popcll(b);
    __syncthreads();
    int off = 0;
    for (int w2 = 0; w2 < wv; w2++) off += wsum[w2];
    int tot = wsum[0] + wsum[1] + wsum[2] + wsum[3];
    int base = sbase;
    if (flag) {
      int pos = base + off + lr;
      if (pos < CAP) {
        tok[e * CAP + pos] = i >> 2;
        wt[e * CAP + pos] = tw[i];
      }
    }
    __syncthreads();
    if (tid == 0) sbase = base + tot;
  }
  __syncthreads();
  if (tid == 0) cnt[e] = min(sbase, CAP);
}

// ---------------- gather: xg[e][t][slot][32k] = xbt[t][tok[e][slot]], zero-padded ----------------
__global__ __launch_bounds__(256) void gather_kernel(const f16* __restrict__ xbt,
                                                     const int* __restrict__ tok,
                                                     const int* __restrict__ cnt,
                                                     f16* __restrict__ xg) {
  int bid = blockIdx.x;
  int t = bid & 63, e = bid >> 6;
  int cn = cnt[e];
  int tid = threadIdx.x;
  char* dst = (char*)xg + (size_t)e * 2097152 + (size_t)t * 32768;
  const char* srcb = (const char*)xbt + (size_t)t * 131072;
  for (int s = tid; s < CAP; s += 256) {
    uint4 v0 = {0,0,0,0}, v1 = {0,0,0,0}, v2 = {0,0,0,0}, v3 = {0,0,0,0};
    if (s < cn) {
      const uint4* sp = (const uint4*)(srcb + (size_t)tok[e * CAP + s] * 64);
      v0 = sp[0]; v1 = sp[1]; v2 = sp[2]; v3 = sp[3];
    }
    uint4* dp = (uint4*)(dst + s * 64);
    dp[0] = v0; dp[1] = v1; dp[2] = v2; dp[3] = v3;
  }
}

// ---------------- barrier-decoupled MFMA GEMM ----------------
// A-fragments: global->VGPR direct (k-chunked layout), prefetched 1 tile ahead.
// B: global->regs (2 tiles ahead) -> fp16 LDS (double-buffered). Barrier gates only B.
// MODE 0: routed up (dual w1/w3, A=xg, silu-mul -> hbuf k-chunked)
// MODE 1: shared up (dual sg/su, A=xbt, -> hs k-chunked)
// MODE 2: routed down (w2, A=hbuf[e], atomicAdd out)
// MODE 3: shared down (sd, A=hs, plain store out)
template<int MODE>
__global__ __launch_bounds__(256, (MODE == 1) ? 3 : ((MODE == 3) ? 4 : 2))
void gemm_kernel(const f16* __restrict__ Ag, const float* __restrict__ B0g,
                 const float* __restrict__ B1g, void* __restrict__ outp,
                 const int* __restrict__ tokL, const float* __restrict__ wtL,
                 const int* __restrict__ cntP) {
  constexpr int BM = (MODE == 0 || MODE == 2) ? 512 : 256;
  constexpr int BN = (MODE == 2) ? 64 : 32;
  constexpr bool DUAL = (MODE <= 1);
  constexpr int MF = BM / 64;
  constexpr int NF = BN / 16;
  constexpr int KD = (MODE == 2) ? 1024 : 2048;
  constexpr int NK = KD / 32;
  constexpr int ND = (MODE == 0) ? 1024 : 2048;
  constexpr int TS = (MODE == 0 || MODE == 2) ? 32768 : 131072;  // A k-tile byte stride
  constexpr int BSZ = (DUAL ? 2 : 1) * BN * 64;

  int bid = blockIdx.x;
  int tid = threadIdx.x, lane = tid & 63, wv = tid >> 6;
  int e = 0, m0 = 0, n0 = 0;
  if constexpr (MODE == 0 || MODE == 2) {
    e = (bid & 7) + ((bid >> 3) >> 5) * 8;   // XCD-clustered experts
    n0 = ((bid >> 3) & 31) * BN;
  } else {
    n0 = ((bid & 7) * 8 + ((bid >> 3) & 7)) * 32;
    m0 = ((bid >> 3) >> 3) * 256;
  }

  const char* Abase = (const char*)Ag;
  const float* B0 = B0g;
  const float* B1 = B1g;
  const int* tokp = tokL;
  const float* wtp = wtL;
  int Mcur = 0;
  if constexpr (MODE == 0 || MODE == 2) {
    Mcur = cntP[e];
    Abase += (size_t)e * ((MODE == 0) ? 2097152 : 1048576);
    B0 += (size_t)e * KD * ND;
    if constexpr (MODE == 0) B1 += (size_t)e * KD * ND;
    tokp += e * CAP;
    wtp += e * CAP;
  }

  __shared__ __align__(16) char bs[2 * BSZ];

  int kb = tid >> 3;                 // B k-row 0..31
  int nbL = (tid & 7) * (BN / 8);    // B n base (4 or 8 cols per thread)

  unsigned voff[MF];
#pragma unroll
  for (int mf = 0; mf < MF; mf++) {
    int row = ((MODE == 0 || MODE == 2) ? (wv * (BM / 4)) : (m0 + wv * 64)) + mf * 16 + (lane & 15);
    voff[mf] = row * 64 + ((lane >> 4) << 4);
  }

  f32x4 acc0[MF][NF];
  f32x4 acc1[DUAL ? MF : 1][DUAL ? NF : 1];
#pragma unroll
  for (int mf = 0; mf < MF; mf++)
#pragma unroll
    for (int nf = 0; nf < NF; nf++) acc0[mf][nf] = (f32x4){0.f, 0.f, 0.f, 0.f};
  if constexpr (DUAL) {
#pragma unroll
    for (int mf = 0; mf < MF; mf++)
#pragma unroll
      for (int nf = 0; nf < NF; nf++) acc1[mf][nf] = (f32x4){0.f, 0.f, 0.f, 0.f};
  }

  half8 af[MF];
  half8 bf0[NF];
  half8 bf1[DUAL ? NF : 1];
  f32x4 bE0, bE1, bO0, bO1;

  auto loadB = [&](int t, f32x4& X, f32x4& Y) {
    const float* s = B0 + (size_t)(t * 32 + kb) * ND + n0 + nbL;
    X = *(const f32x4*)s;
    if constexpr (DUAL) {
      Y = *(const f32x4*)(B1 + (size_t)(t * 32 + kb) * ND + n0 + nbL);
    } else if constexpr (MODE == 2) {
      Y = *(const f32x4*)(s + 4);
    }
  };
  auto writeB = [&](const f32x4& X, const f32x4& Y, int par) {
    char* base = bs + par * BSZ;
#pragma unroll
    for (int q = 0; q < 4; q++) {
      int n = nbL + q;
      int off = n * 64 + (((kb >> 3) ^ swz3(n)) << 4) + (kb & 7) * 2;
      *(f16*)(base + off) = (f16)X[q];
      if constexpr (DUAL) {
        *(f16*)(base + BN * 64 + off) = (f16)Y[q];
      } else if constexpr (MODE == 2) {
        int n2 = n + 4;
        int off2 = n2 * 64 + (((kb >> 3) ^ swz3(n2)) << 4) + (kb & 7) * 2;
        *(f16*)(base + off2) = (f16)Y[q];
      }
    }
  };
  auto bfread = [&](int par) {
#pragma unroll
    for (int nf = 0; nf < NF; nf++) {
      int n = nf * 16 + (lane & 15);
      int off = par * BSZ + n * 64 + (((lane >> 4) ^ swz3(n)) << 4);
      bf0[nf] = *(const half8*)(bs + off);
      if constexpr (DUAL) bf1[nf] = *(const half8*)(bs + BN * 64 + off);
    }
  };
  auto loadAf = [&](int t) {
#pragma unroll
    for (int mf = 0; mf < MF; mf++)
      af[mf] = *(const half8*)(Abase + (size_t)t * TS + voff[mf]);
  };
  auto domfma = [&]() {
#pragma unroll
    for (int mf = 0; mf < MF; mf++)
#pragma unroll
      for (int nf = 0; nf < NF; nf++) {
        acc0[mf][nf] = __builtin_amdgcn_mfma_f32_16x16x32_f16(af[mf], bf0[nf], acc0[mf][nf], 0, 0, 0);
        if constexpr (DUAL)
          acc1[mf][nf] = __builtin_amdgcn_mfma_f32_16x16x32_f16(af[mf], bf1[nf], acc1[mf][nf], 0, 0, 0);
      }
  };

  // Prologue
  loadB(0, bE0, bE1);
  loadB(1, bO0, bO1);
  loadAf(0);
  writeB(bE0, bE1, 0);        // auto-waits B(0) regs only
  asm volatile("s_waitcnt lgkmcnt(0)" ::: "memory");
  __builtin_amdgcn_s_barrier();

  for (int t = 0; t < NK; t += 2) {
    // tile t (parity 0)
    bfread(0);
    writeB(bO0, bO1, 1);                 // publish B(t+1)
    if (t + 2 < NK) loadB(t + 2, bE0, bE1);
    domfma();                            // af(t), loaded one tile ago
    loadAf(t + 1 < NK ? t + 1 : t);      // prefetch af(t+1)
    asm volatile("s_waitcnt lgkmcnt(0)" ::: "memory");
    __builtin_amdgcn_s_barrier();
    // tile t+1 (parity 1)
    bfread(1);
    if (t + 2 < NK) writeB(bE0, bE1, 0); // publish B(t+2)
    if (t + 3 < NK) loadB(t + 3, bO0, bO1);
    domfma();                            // af(t+1)
    if (t + 2 < NK) {
      loadAf(t + 2);
      asm volatile("s_waitcnt lgkmcnt(0)" ::: "memory");
      __builtin_amdgcn_s_barrier();
    }
  }

  // epilogue
  int koff = (lane >> 4) << 2;
  if constexpr (MODE == 0) {
    char* Hb = (char*)outp + (size_t)e * 1048576;
#pragma unroll
    for (int mf = 0; mf < MF; mf++)
#pragma unroll
      for (int j = 0; j < 4; j++) {
        int slot = wv * 128 + mf * 16 + koff + j;
#pragma unroll
        for (int nf = 0; nf < NF; nf++) {
          int col = n0 + nf * 16 + (lane & 15);
          float g = acc0[mf][nf][j], u = acc1[mf][nf][j];
          float val = g / (1.f + expf(-g)) * u;
          *(f16*)(Hb + (size_t)(col >> 5) * 32768 + slot * 64 + (col & 31) * 2) = (f16)val;
        }
      }
  } else if constexpr (MODE == 1) {
    char* Hb = (char*)outp;
#pragma unroll
    for (int mf = 0; mf < MF; mf++)
#pragma unroll
      for (int j = 0; j < 4; j++) {
        int row = m0 + wv * 64 + mf * 16 + koff + j;
#pragma unroll
        for (int nf = 0; nf < NF; nf++) {
          int col = n0 + nf * 16 + (lane & 15);
          float g = acc0[mf][nf][j], u = acc1[mf][nf][j];
          float val = g / (1.f + expf(-g)) * u;
          *(f16*)(Hb + (size_t)(col >> 5) * 131072 + row * 64 + (col & 31) * 2) = (f16)val;
        }
      }
  } else if constexpr (MODE == 2) {
    float* Of = (float*)outp;
#pragma unroll
    for (int mf = 0; mf < MF; mf++)
#pragma unroll
      for (int j = 0; j < 4; j++) {
        int slot = wv * 128 + mf * 16 + koff + j;
        if (slot < Mcur) {
          int tk = tokp[slot];
          float w = wtp[slot];
#pragma unroll
          for (int nf = 0; nf < NF; nf++) {
            int col = n0 + nf * 16 + (lane & 15);
            atomicAdd(Of + (size_t)tk * HDIM + col, acc0[mf][nf][j] * w);
          }
        }
      }
  } else {
    float* Of = (float*)outp;
#pragma unroll
    for (int mf = 0; mf < MF; mf++)
#pragma unroll
      for (int j = 0; j < 4; j++) {
        int row = m0 + wv * 64 + mf * 16 + koff + j;
#pragma unroll
        for (int nf = 0; nf < NF; nf++) {
          int col = n0 + nf * 16 + (lane & 15);
          Of[(size_t)row * HDIM + col] = acc0[mf][nf][j];
        }
      }
  }
}

// ---------------- launch ----------------
extern "C" void kernel_launch(void* const* d_in, const int* in_sizes, int n_in,
                              void* d_out, int out_size, void* d_ws, size_t ws_size,
                              hipStream_t stream) {
  const float* x  = (const float*)d_in[0];
  const float* gw = (const float*)d_in[1];
  const float* gb = (const float*)d_in[2];
  const float* w1 = (const float*)d_in[3];
  const float* w2 = (const float*)d_in[4];
  const float* w3 = (const float*)d_in[5];
  const float* sg = (const float*)d_in[6];
  const float* su = (const float*)d_in[7];
  const float* sd = (const float*)d_in[8];
  float* out = (float*)d_out;
  char* ws = (char*)d_ws;

  f16*   xbt = (f16*)(ws);                 // 8 MB  k-chunked x fp16
  f16*   hs  = (f16*)(ws + 8388608);       // 8 MB  k-chunked shared-mid
  f16*   hbuf= (f16*)(ws + 16777216);      // 32 MB k-chunked routed-mid
  f16*   xg  = (f16*)(ws + 50331648);      // 64 MB compact gathered A
  int*   tok = (int*)(ws + 117440512);
  float* wt  = (float*)(ws + 117506048);
  int*   tidx= (int*)(ws + 117571584);
  float* tw  = (float*)(ws + 117604352);
  int*   cnt = (int*)(ws + 117637120);

  convert_kernel<<<2048, 256, 0, stream>>>(x, xbt);
  gate_kernel<<<2048, 256, 0, stream>>>(x, gw, gb, tidx, tw);
  dispatch_kernel<<<32, 256, 0, stream>>>(tidx, tw, tok, wt, cnt);
  gather_kernel<<<2048, 256, 0, stream>>>(xbt, tok, cnt, xg);

  // routed up: hbuf = silu(Xg@w1)*(Xg@w3)   grid = 32n x 32e
  gemm_kernel<0><<<1024, 256, 0, stream>>>(xg, w1, w3, hbuf, tok, wt, cnt);
  // shared up: hs = silu(x@sg)*(x@su)       grid = 64n x 8m
  gemm_kernel<1><<<512, 256, 0, stream>>>(xbt, sg, su, hs, nullptr, nullptr, nullptr);
  // shared down: out = hs @ sd              grid = 64n x 8m
  gemm_kernel<3><<<512, 256, 0, stream>>>(hs, sd, nullptr, out, nullptr, nullptr, nullptr);
  // routed down: out += w * (hbuf @ w2)     grid = 32n x 32e
  gemm_kernel<2><<<1024, 256, 0, stream>>>(hbuf, w2, nullptr, out, tok, wt, cnt);
}